// Round 2
// baseline (4171.581 us; speedup 1.0000x reference)
//
#include <hip/hip_runtime.h>
#include <hip/hip_bf16.h>
#include <math.h>

typedef __hip_bfloat16 bf16;

// Problem constants (from reference setup_inputs)
#define BB 4
#define TT 4096
#define DD 1024
#define KCONV 4
#define NCHUNK 16
#define TCHUNK (TT / NCHUNK)   // 256

__device__ __forceinline__ float sigmoidf_(float x) {
  return 1.0f / (1.0f + expf(-x));
}

__device__ __forceinline__ void store_elem(float* C, size_t idx, float v) {
  C[idx] = v;
}
__device__ __forceinline__ void store_elem(bf16* C, size_t idx, float v) {
  C[idx] = __float2bfloat16(v);
}

// ---------------------------------------------------------------------------
// Kernel 1 (per batch): xm = x + causal_dwconv(x), output bf16
// ---------------------------------------------------------------------------
__global__ __launch_bounds__(256) void conv_add_kernel(
    const float* __restrict__ x, const float* __restrict__ Wc,
    bf16* __restrict__ xm) {
  int i = blockIdx.x * 256 + threadIdx.x;  // over t*d (single batch)
  int c = i % DD;
  int t = i / DD;
  float w0 = Wc[c * 4 + 0], w1 = Wc[c * 4 + 1], w2 = Wc[c * 4 + 2],
        w3 = Wc[c * 4 + 3];
  float xv = x[i];
  float acc = xv + w3 * xv;                   // j=3 -> tap at t
  if (t >= 1) acc += w2 * x[i - DD];
  if (t >= 2) acc += w1 * x[i - 2 * DD];
  if (t >= 3) acc += w0 * x[i - 3 * DD];
  xm[i] = __float2bfloat16(acc);
}

// ---------------------------------------------------------------------------
// Tiled GEMM:  C[m][n] = sum_k A[m][k] * B[n][k]   (A bf16 [M][K], B fp32
// [N][K], C fp32 or bf16). BM=BN=64, BK=16, 256 threads, 4x4 microtile.
// ---------------------------------------------------------------------------
#define BM 64
#define BN 64
#define BKK 16

template <typename TOut>
__global__ __launch_bounds__(256) void gemm_nt_kernel(
    const bf16* __restrict__ A, const float* __restrict__ B,
    TOut* __restrict__ C, int M, int N, int K) {
  __shared__ float As[BKK][BM + 1];
  __shared__ float Bs[BKK][BN + 1];
  const int n0 = blockIdx.x * BN;
  const int m0 = blockIdx.y * BM;
  const int tid = threadIdx.x;
  const int tx = tid & 15;   // n microtile index
  const int ty = tid >> 4;   // m microtile index
  const int lk = tid & 15;   // k index for loads
  const int lr = tid >> 4;   // row base for loads

  float acc[4][4] = {};

  for (int k0 = 0; k0 < K; k0 += BKK) {
#pragma unroll
    for (int p = 0; p < 4; ++p) {
      As[lk][lr + 16 * p] = __bfloat162float(
          A[(size_t)(m0 + lr + 16 * p) * K + (k0 + lk)]);
      Bs[lk][lr + 16 * p] =
          B[(size_t)(n0 + lr + 16 * p) * K + (k0 + lk)];
    }
    __syncthreads();
#pragma unroll
    for (int kk = 0; kk < BKK; ++kk) {
      float a[4], b[4];
#pragma unroll
      for (int i = 0; i < 4; ++i) a[i] = As[kk][ty * 4 + i];
#pragma unroll
      for (int j = 0; j < 4; ++j) b[j] = Bs[kk][tx * 4 + j];
#pragma unroll
      for (int i = 0; i < 4; ++i)
#pragma unroll
        for (int j = 0; j < 4; ++j) acc[i][j] += a[i] * b[j];
    }
    __syncthreads();
  }

#pragma unroll
  for (int i = 0; i < 4; ++i)
#pragma unroll
    for (int j = 0; j < 4; ++j)
      store_elem(C, (size_t)(m0 + ty * 4 + i) * N + (n0 + tx * 4 + j),
                 acc[i][j]);
}

// ---------------------------------------------------------------------------
// Chunked linear scan over one batch.
// u layout [t][4d] bf16: v = u[...,0:d], gate = [d:2d], decay = [2d:3d],
// inject = [3d:4d].
// ---------------------------------------------------------------------------
__global__ __launch_bounds__(256) void scan_chunk_kernel(
    const bf16* __restrict__ u, float* __restrict__ cA,
    float* __restrict__ cB) {
  int idx = blockIdx.x * 256 + threadIdx.x;  // NCHUNK * DD
  int c = idx % DD;
  int chunk = idx / DD;
  float Aacc = 1.0f, Bacc = 0.0f;
  int t0 = chunk * TCHUNK;
  for (int t = t0; t < t0 + TCHUNK; ++t) {
    const bf16* row = u + (size_t)t * 4 * DD;
    float dec = sigmoidf_(__bfloat162float(row[2 * DD + c]));
    float inj = tanhf(__bfloat162float(row[3 * DD + c]));
    Aacc *= dec;
    Bacc = dec * Bacc + (1.0f - dec) * inj;
  }
  cA[idx] = Aacc;
  cB[idx] = Bacc;
}

__global__ __launch_bounds__(256) void scan_prefix_kernel(
    const float* __restrict__ cA, const float* __restrict__ cB,
    float* __restrict__ S) {
  int c = blockIdx.x * 256 + threadIdx.x;  // DD
  float s = 0.0f;
  for (int j = 0; j < NCHUNK; ++j) {
    int e = j * DD + c;
    S[e] = s;
    s = cA[e] * s + cB[e];
  }
}

__global__ __launch_bounds__(256) void scan_out_kernel(
    const bf16* __restrict__ u, const float* __restrict__ S,
    bf16* __restrict__ y) {
  int idx = blockIdx.x * 256 + threadIdx.x;  // NCHUNK * DD
  int c = idx % DD;
  int chunk = idx / DD;
  float state = S[idx];
  int t0 = chunk * TCHUNK;
  for (int t = t0; t < t0 + TCHUNK; ++t) {
    const bf16* row = u + (size_t)t * 4 * DD;
    float v = __bfloat162float(row[c]);
    float g = sigmoidf_(__bfloat162float(row[DD + c]));
    float dec = sigmoidf_(__bfloat162float(row[2 * DD + c]));
    float inj = tanhf(__bfloat162float(row[3 * DD + c]));
    state = dec * state + (1.0f - dec) * inj;
    y[(size_t)t * DD + c] = __float2bfloat16(g * v + (1.0f - g) * state);
  }
}

// ---------------------------------------------------------------------------
extern "C" void kernel_launch(void* const* d_in, const int* in_sizes, int n_in,
                              void* d_out, int out_size, void* d_ws,
                              size_t ws_size, hipStream_t stream) {
  const float* x = (const float*)d_in[0];      // [b,t,d]
  const float* Wc = (const float*)d_in[1];     // [d,1,4]
  const float* Wp = (const float*)d_in[2];     // [4d,d]
  const float* Wo = (const float*)d_in[3];     // [d,d]
  float* out = (float*)d_out;                  // [b,t,d]

  const size_t nb = (size_t)TT * DD;  // 4,194,304 per-batch elements

  // Workspace layout (per-batch buffers, reused across b):
  //   xm : nb bf16            ( 8 MiB)
  //   u  : 4*nb bf16          (32 MiB)
  //   y  : nb bf16            ( 8 MiB)
  //   cA, cB, S : NCHUNK*DD fp32 each (64 KiB each)
  char* p = (char*)d_ws;
  bf16* xm = (bf16*)p;             p += nb * sizeof(bf16);
  bf16* u  = (bf16*)p;             p += 4 * nb * sizeof(bf16);
  bf16* y  = (bf16*)p;             p += nb * sizeof(bf16);
  float* cA = (float*)p;           p += NCHUNK * DD * sizeof(float);
  float* cB = (float*)p;           p += NCHUNK * DD * sizeof(float);
  float* S  = (float*)p;

  for (int b = 0; b < BB; ++b) {
    const float* xb = x + (size_t)b * nb;
    float* outb = out + (size_t)b * nb;

    // 1. conv + add -> xm (bf16)
    conv_add_kernel<<<(int)(nb / 256), 256, 0, stream>>>(xb, Wc, xm);

    // 2. u = xm @ Wp^T   (M=4096, N=4096, K=1024), bf16 out
    {
      dim3 grid(4 * DD / BN, TT / BM);
      gemm_nt_kernel<bf16><<<grid, 256, 0, stream>>>(xm, Wp, u, TT, 4 * DD, DD);
    }

    // 3. chunked scan -> y (bf16)
    {
      int nthreads = NCHUNK * DD;  // 16384
      scan_chunk_kernel<<<nthreads / 256, 256, 0, stream>>>(u, cA, cB);
      scan_prefix_kernel<<<DD / 256, 256, 0, stream>>>(cA, cB, S);
      scan_out_kernel<<<nthreads / 256, 256, 0, stream>>>(u, S, y);
    }

    // 4. out_b = y @ Wo^T   (M=4096, N=1024, K=1024), fp32 out
    {
      dim3 grid(DD / BN, TT / BM);
      gemm_nt_kernel<float><<<grid, 256, 0, stream>>>(y, Wo, outb, TT, DD, DD);
    }
  }
}

// Round 3
// 438.593 us; speedup vs baseline: 9.5113x; 9.5113x over previous
//
#include <hip/hip_runtime.h>
#include <hip/hip_bf16.h>
#include <math.h>

typedef __hip_bfloat16 bf16;
typedef __bf16 bf16x8 __attribute__((ext_vector_type(8)));
typedef float f32x4 __attribute__((ext_vector_type(4)));

// Problem constants
#define BB 4
#define TT 4096
#define DD 1024

__device__ __forceinline__ float sigmoidf_(float x) {
  return 1.0f / (1.0f + expf(-x));
}

// ---------------------------------------------------------------------------
// Weight fp32 -> bf16 conversion
// ---------------------------------------------------------------------------
__global__ __launch_bounds__(256) void w2bf_kernel(const float* __restrict__ w,
                                                   bf16* __restrict__ o,
                                                   int n) {
  int i = blockIdx.x * 256 + threadIdx.x;
  if (i < n) o[i] = __float2bfloat16(w[i]);
}

// ---------------------------------------------------------------------------
// conv + add -> bf16  (works over nbat contiguous batches)
// ---------------------------------------------------------------------------
__global__ __launch_bounds__(256) void conv_add_kernel(
    const float* __restrict__ x, const float* __restrict__ Wc,
    bf16* __restrict__ xm, int total) {
  int i = blockIdx.x * 256 + threadIdx.x;
  if (i >= total) return;
  int c = i % DD;
  int t = (i / DD) % TT;
  float w0 = Wc[c * 4 + 0], w1 = Wc[c * 4 + 1], w2 = Wc[c * 4 + 2],
        w3 = Wc[c * 4 + 3];
  float xv = x[i];
  float acc = xv + w3 * xv;
  if (t >= 1) acc += w2 * x[i - DD];
  if (t >= 2) acc += w1 * x[i - 2 * DD];
  if (t >= 3) acc += w0 * x[i - 3 * DD];
  xm[i] = __float2bfloat16(acc);
}

// ---------------------------------------------------------------------------
// MFMA GEMM:  C[m][n] = sum_k A[m][k] * B[n][k]   (A,B bf16 row-major-K)
// 128x128 tile, BK=32, 256 threads (4 waves, 2x2), 16x16x32 bf16 MFMA,
// global_load_lds width-16 staging, 2-barrier loop (m97 structure).
// EP=0: C fp32 plain.  EP=1: C bf16 with per-1024-column activation
//       (class 0: none, 1/2: sigmoid, 3: tanh) — for the fused proj GEMM.
// ---------------------------------------------------------------------------
template <int EP>
__global__ __launch_bounds__(256) void gemm_mfma_kernel(
    const bf16* __restrict__ A, const bf16* __restrict__ B,
    void* __restrict__ C, int M, int N, int K) {
  __shared__ bf16 As[128 * 32];
  __shared__ bf16 Bs[128 * 32];
  const int tid = threadIdx.x;
  const int wave = tid >> 6, lane = tid & 63;
  const int wr = wave >> 1, wc = wave & 1;
  const int m0 = blockIdx.y * 128, n0 = blockIdx.x * 128;

  // staging decomposition: 8 chunks of 1KB per tile; wave handles 2 chunks.
  const int srow = lane >> 2;          // row within 16-row chunk
  const int selem = (lane & 3) * 8;    // bf16 element offset within row

  f32x4 acc[4][4];
#pragma unroll
  for (int i = 0; i < 4; ++i)
#pragma unroll
    for (int j = 0; j < 4; ++j) acc[i][j] = (f32x4)0.0f;

  for (int k0 = 0; k0 < K; k0 += 32) {
#pragma unroll
    for (int h = 0; h < 2; ++h) {
      const int chunk = wave * 2 + h;
      const int row = chunk * 16 + srow;
      const bf16* ga = A + (size_t)(m0 + row) * K + k0 + selem;
      const bf16* gb = B + (size_t)(n0 + row) * K + k0 + selem;
      __builtin_amdgcn_global_load_lds(
          (const __attribute__((address_space(1))) void*)ga,
          (__attribute__((address_space(3))) void*)&As[chunk * 512], 16, 0, 0);
      __builtin_amdgcn_global_load_lds(
          (const __attribute__((address_space(1))) void*)gb,
          (__attribute__((address_space(3))) void*)&Bs[chunk * 512], 16, 0, 0);
    }
    __syncthreads();  // drains vmcnt — global_load_lds complete

    bf16x8 af[4], bfv[4];
#pragma unroll
    for (int m = 0; m < 4; ++m)
      af[m] = *(const bf16x8*)&As[(wr * 64 + m * 16 + (lane & 15)) * 32 +
                                  (lane >> 4) * 8];
#pragma unroll
    for (int n = 0; n < 4; ++n)
      bfv[n] = *(const bf16x8*)&Bs[(wc * 64 + n * 16 + (lane & 15)) * 32 +
                                   (lane >> 4) * 8];
#pragma unroll
    for (int m = 0; m < 4; ++m)
#pragma unroll
      for (int n = 0; n < 4; ++n)
        acc[m][n] = __builtin_amdgcn_mfma_f32_16x16x32_bf16(
            af[m], bfv[n], acc[m][n], 0, 0, 0);
    __syncthreads();  // before next stage overwrites LDS
  }

  // epilogue: C/D layout col=lane&15, row=(lane>>4)*4+j
  const int actClass = (EP == 1) ? (n0 >> 10) : 0;  // block-uniform (128|1024)
#pragma unroll
  for (int m = 0; m < 4; ++m) {
    const int row = m0 + wr * 64 + m * 16 + (lane >> 4) * 4;
#pragma unroll
    for (int n = 0; n < 4; ++n) {
      const int col = n0 + wc * 64 + n * 16 + (lane & 15);
#pragma unroll
      for (int j = 0; j < 4; ++j) {
        float v = acc[m][n][j];
        if (EP == 0) {
          ((float*)C)[(size_t)(row + j) * N + col] = v;
        } else {
          if (actClass == 1 || actClass == 2) v = sigmoidf_(v);
          else if (actClass == 3) v = tanhf(v);
          ((bf16*)C)[(size_t)(row + j) * N + col] = __float2bfloat16(v);
        }
      }
    }
  }
}

// ---------------------------------------------------------------------------
// Fallback fp32-B GEMM (tier2 out-proj only): A bf16, B fp32, C fp32.
// ---------------------------------------------------------------------------
#define BM 64
#define BN 64
#define BKK 16
__global__ __launch_bounds__(256) void gemm_nt_kernel(
    const bf16* __restrict__ A, const float* __restrict__ B,
    float* __restrict__ C, int M, int N, int K) {
  __shared__ float Asm[BKK][BM + 1];
  __shared__ float Bsm[BKK][BN + 1];
  const int n0 = blockIdx.x * BN;
  const int m0 = blockIdx.y * BM;
  const int tid = threadIdx.x;
  const int tx = tid & 15, ty = tid >> 4;
  const int lk = tid & 15, lr = tid >> 4;
  float acc[4][4] = {};
  for (int k0 = 0; k0 < K; k0 += BKK) {
#pragma unroll
    for (int p = 0; p < 4; ++p) {
      Asm[lk][lr + 16 * p] =
          __bfloat162float(A[(size_t)(m0 + lr + 16 * p) * K + (k0 + lk)]);
      Bsm[lk][lr + 16 * p] = B[(size_t)(n0 + lr + 16 * p) * K + (k0 + lk)];
    }
    __syncthreads();
#pragma unroll
    for (int kk = 0; kk < BKK; ++kk) {
      float a[4], b[4];
#pragma unroll
      for (int i = 0; i < 4; ++i) a[i] = Asm[kk][ty * 4 + i];
#pragma unroll
      for (int j = 0; j < 4; ++j) b[j] = Bsm[kk][tx * 4 + j];
#pragma unroll
      for (int i = 0; i < 4; ++i)
#pragma unroll
        for (int j = 0; j < 4; ++j) acc[i][j] += a[i] * b[j];
    }
    __syncthreads();
  }
#pragma unroll
  for (int i = 0; i < 4; ++i)
#pragma unroll
    for (int j = 0; j < 4; ++j)
      C[(size_t)(m0 + ty * 4 + i) * N + (n0 + tx * 4 + j)] = acc[i][j];
}

// ---------------------------------------------------------------------------
// Chunked scan. u holds ALREADY-ACTIVATED planes (v, g, dec, inj) in bf16.
// ---------------------------------------------------------------------------
__global__ __launch_bounds__(256) void scan_chunk_kernel(
    const bf16* __restrict__ u, float* __restrict__ cA,
    float* __restrict__ cB, int nchunk, int tchunk) {
  int idx = blockIdx.x * 256 + threadIdx.x;  // nbat*nchunk*DD
  int c = idx % DD;
  int chunk = (idx / DD) % nchunk;
  int b = idx / (DD * nchunk);
  const bf16* ub = u + (size_t)b * TT * 4 * DD;
  float Aacc = 1.0f, Bacc = 0.0f;
  int t0 = chunk * tchunk;
  for (int t = t0; t < t0 + tchunk; ++t) {
    const bf16* row = ub + (size_t)t * 4 * DD;
    float dec = __bfloat162float(row[2 * DD + c]);
    float inj = __bfloat162float(row[3 * DD + c]);
    Aacc *= dec;
    Bacc = dec * Bacc + (1.0f - dec) * inj;
  }
  cA[idx] = Aacc;
  cB[idx] = Bacc;
}

__global__ __launch_bounds__(256) void scan_prefix_kernel(
    const float* __restrict__ cA, const float* __restrict__ cB,
    float* __restrict__ S, int nchunk) {
  int idx = blockIdx.x * 256 + threadIdx.x;  // nbat*DD
  int c = idx % DD;
  int b = idx / DD;
  float s = 0.0f;
  for (int j = 0; j < nchunk; ++j) {
    int e = (b * nchunk + j) * DD + c;
    S[e] = s;
    s = cA[e] * s + cB[e];
  }
}

__global__ __launch_bounds__(256) void scan_out_kernel(
    const bf16* __restrict__ u, const float* __restrict__ S,
    bf16* __restrict__ y, int nchunk, int tchunk) {
  int idx = blockIdx.x * 256 + threadIdx.x;  // nbat*nchunk*DD
  int c = idx % DD;
  int chunk = (idx / DD) % nchunk;
  int b = idx / (DD * nchunk);
  const bf16* ub = u + (size_t)b * TT * 4 * DD;
  bf16* yb = y + (size_t)b * TT * DD;
  float state = S[idx];
  int t0 = chunk * tchunk;
  for (int t = t0; t < t0 + tchunk; ++t) {
    const bf16* row = ub + (size_t)t * 4 * DD;
    float v = __bfloat162float(row[c]);
    float g = __bfloat162float(row[DD + c]);
    float dec = __bfloat162float(row[2 * DD + c]);
    float inj = __bfloat162float(row[3 * DD + c]);
    state = dec * state + (1.0f - dec) * inj;
    yb[(size_t)t * DD + c] = __float2bfloat16(g * v + (1.0f - g) * state);
  }
}

// ---------------------------------------------------------------------------
extern "C" void kernel_launch(void* const* d_in, const int* in_sizes, int n_in,
                              void* d_out, int out_size, void* d_ws,
                              size_t ws_size, hipStream_t stream) {
  const float* x = (const float*)d_in[0];
  const float* Wc = (const float*)d_in[1];
  const float* Wp = (const float*)d_in[2];
  const float* Wo = (const float*)d_in[3];
  float* out = (float*)d_out;

  const size_t nb = (size_t)TT * DD;

  auto need = [&](int nbat, int nchunk, bool wob) -> size_t {
    return (size_t)nbat * nb * 2          // xm (shared with y)
           + (size_t)nbat * 4 * nb * 2    // u
           + (size_t)4 * DD * DD * 2      // Wp bf16
           + (wob ? (size_t)DD * DD * 2 : 0)
           + (size_t)3 * nbat * nchunk * DD * 4;  // cA,cB,S
  };

  int nbat, nchunk;
  bool haveWob;
  if (ws_size >= need(4, 64, true)) {
    nbat = 4; nchunk = 64; haveWob = true;
  } else if (ws_size >= need(1, 64, true)) {
    nbat = 1; nchunk = 64; haveWob = true;
  } else {
    nbat = 1; nchunk = 16; haveWob = false;  // == round-1 known-good footprint
  }
  const int tchunk = TT / nchunk;

  char* p = (char*)d_ws;
  bf16* Wpb = (bf16*)p;  p += (size_t)4 * DD * DD * 2;
  bf16* Wob = nullptr;
  if (haveWob) { Wob = (bf16*)p; p += (size_t)DD * DD * 2; }
  bf16* xm = (bf16*)p;   p += (size_t)nbat * nb * 2;   // also y
  bf16* u = (bf16*)p;    p += (size_t)nbat * 4 * nb * 2;
  float* cA = (float*)p; p += (size_t)nbat * nchunk * DD * 4;
  float* cB = (float*)p; p += (size_t)nbat * nchunk * DD * 4;
  float* S = (float*)p;
  bf16* y = xm;  // xm consumed by GEMM1 before scan_out writes y

  // weight conversion (every call; deterministic)
  w2bf_kernel<<<(4 * DD * DD) / 256, 256, 0, stream>>>(Wp, Wpb, 4 * DD * DD);
  if (haveWob)
    w2bf_kernel<<<(DD * DD) / 256, 256, 0, stream>>>(Wo, Wob, DD * DD);

  for (int b0 = 0; b0 < BB; b0 += nbat) {
    const float* xb = x + (size_t)b0 * nb;
    float* outb = out + (size_t)b0 * nb;
    const int Mtot = nbat * TT;
    const int total = (int)(nbat * nb);

    conv_add_kernel<<<total / 256, 256, 0, stream>>>(xb, Wc, xm, total);

    {
      dim3 grid(4 * DD / 128, Mtot / 128);
      gemm_mfma_kernel<1><<<grid, 256, 0, stream>>>(xm, Wpb, u, Mtot, 4 * DD,
                                                    DD);
    }
    {
      int nthreads = nbat * nchunk * DD;
      scan_chunk_kernel<<<nthreads / 256, 256, 0, stream>>>(u, cA, cB, nchunk,
                                                            tchunk);
      scan_prefix_kernel<<<(nbat * DD) / 256, 256, 0, stream>>>(cA, cB, S,
                                                                nchunk);
      scan_out_kernel<<<nthreads / 256, 256, 0, stream>>>(u, S, y, nchunk,
                                                          tchunk);
    }
    if (haveWob) {
      dim3 grid(DD / 128, Mtot / 128);
      gemm_mfma_kernel<0><<<grid, 256, 0, stream>>>(y, Wob, outb, Mtot, DD, DD);
    } else {
      dim3 grid(DD / BN, Mtot / BM);
      gemm_nt_kernel<<<grid, 256, 0, stream>>>(y, Wo, outb, Mtot, DD, DD);
    }
  }
}

// Round 4
// 372.388 us; speedup vs baseline: 11.2023x; 1.1778x over previous
//
#include <hip/hip_runtime.h>
#include <hip/hip_bf16.h>
#include <math.h>

typedef __hip_bfloat16 bf16;
typedef __bf16 bf16x8 __attribute__((ext_vector_type(8)));
typedef float f32x4 __attribute__((ext_vector_type(4)));

// Problem constants
#define BB 4
#define TT 4096
#define DD 1024

__device__ __forceinline__ float fast_sigmoid(float x) {
  return 1.0f / (1.0f + __expf(-x));
}
__device__ __forceinline__ float fast_tanh(float x) {
  return 2.0f / (1.0f + __expf(-2.0f * x)) - 1.0f;
}

// ---------------------------------------------------------------------------
// Weight fp32 -> bf16
// ---------------------------------------------------------------------------
__global__ __launch_bounds__(256) void w2bf_kernel(const float* __restrict__ w,
                                                   bf16* __restrict__ o,
                                                   int n) {
  int i = blockIdx.x * 256 + threadIdx.x;
  if (i < n) o[i] = __float2bfloat16(w[i]);
}

// ---------------------------------------------------------------------------
// conv + add -> bf16
// ---------------------------------------------------------------------------
__global__ __launch_bounds__(256) void conv_add_kernel(
    const float* __restrict__ x, const float* __restrict__ Wc,
    bf16* __restrict__ xm, int total) {
  int i = blockIdx.x * 256 + threadIdx.x;
  if (i >= total) return;
  int c = i % DD;
  int t = (i / DD) % TT;
  float w0 = Wc[c * 4 + 0], w1 = Wc[c * 4 + 1], w2 = Wc[c * 4 + 2],
        w3 = Wc[c * 4 + 3];
  float xv = x[i];
  float acc = xv + w3 * xv;
  if (t >= 1) acc += w2 * x[i - DD];
  if (t >= 2) acc += w1 * x[i - 2 * DD];
  if (t >= 3) acc += w0 * x[i - 3 * DD];
  xm[i] = __float2bfloat16(acc);
}

// ---------------------------------------------------------------------------
// 256x256 8-phase MFMA GEMM (m201-style template, plain HIP).
// C[m][n] = sum_k A[m][k]*B[n][k]; A,B bf16 (row stride K), K % 128 == 0,
// M,N % 256 == 0. 512 threads = 8 waves (2M x 4N); per-wave C = 128x64.
// LDS: 2 slots x 2 halves x [128][64] bf16 for A and B = 128 KiB.
// st_16x32 swizzle: phys_byte = log_byte ^ ((log_byte>>9 & 1) << 5), applied
// per 16 KiB half-region; staged via pre-swizzled GLOBAL source (LDS dest
// linear), read via XOR on the ds_read address (rule #21 involution).
// EP=0: fp32 C.  EP=1: bf16 C with per-1024-col activation
// (0:none, 1/2:sigmoid, 3:tanh).
// ---------------------------------------------------------------------------
template <int EP>
__global__ __launch_bounds__(512) void gemm256_kernel(
    const bf16* __restrict__ A, const bf16* __restrict__ B,
    void* __restrict__ C, int M, int N, int K, int MB) {
  __shared__ __align__(16) bf16 As[2][2][128][64];
  __shared__ __align__(16) bf16 Bs[2][2][128][64];

  const int tid = threadIdx.x;
  const int wv = tid >> 6, l = tid & 63;
  const int wm = wv >> 2, wn = wv & 3;

  // XCD-bijective block swizzle (nwg % 8 == 0 for all our grids)
  const int nwg = gridDim.x;
  const int cpx = nwg >> 3;
  const int bid = blockIdx.x;
  const int wg = (bid & 7) * cpx + (bid >> 3);
  const int bm = wg % MB, bn = wg / MB;
  const int m0 = bm * 256, n0 = bn * 256;

  // staging constants: segment = wv*2+j covers rows seg*8..seg*8+7 of a half.
  // physical byte p = seg*1024 + l*16; bit9 of p == (l>=32); source logical
  // offset = p ^ ((l>=32)?32:0)  ->  row = seg*8 + (l>>3),
  // col_e = ((l&7)*8) ^ ((l>=32)?16:0).
  const int lr3 = l >> 3;
  const int gcolE = ((l & 7) * 8) ^ ((l >= 32) ? 16 : 0);
  // frag-read constants: row = *16 + (l&15) -> row&4 == l&4.
  const int l15 = l & 15;
  const int xorE = (l & 4) ? 16 : 0;
  const int lhi8 = (l >> 4) * 8;
  const int colK[2] = {lhi8 ^ xorE, (32 + lhi8) ^ xorE};

  const bf16* Arow = A + (size_t)(m0 + wv * 16 + lr3) * K + gcolE;
  const bf16* Brow = B + (size_t)(n0 + wv * 16 + lr3) * K + gcolE;

  // half-tile order within K-tile: 0=B.h0, 1=B.h1, 2=A.h0, 3=A.h1
  auto stage = [&](int ht) {
    const int kt = ht >> 2, which = ht & 3;
    const int slot = kt & 1;
    const int k0 = kt * 64;
    if (which < 2) {
      const int half = which;
#pragma unroll
      for (int j = 0; j < 2; ++j) {
        const bf16* src = Brow + (size_t)(half * 128 + j * 8) * K + k0;
        __builtin_amdgcn_global_load_lds(
            (const __attribute__((address_space(1))) void*)src,
            (__attribute__((address_space(3))) void*)(&Bs[slot][half][0][0] +
                                                      wv * 1024 + j * 512),
            16, 0, 0);
      }
    } else {
      const int half = which - 2;
#pragma unroll
      for (int j = 0; j < 2; ++j) {
        const bf16* src = Arow + (size_t)(half * 128 + j * 8) * K + k0;
        __builtin_amdgcn_global_load_lds(
            (const __attribute__((address_space(1))) void*)src,
            (__attribute__((address_space(3))) void*)(&As[slot][half][0][0] +
                                                      wv * 1024 + j * 512),
            16, 0, 0);
      }
    }
  };

  f32x4 acc[8][4];
#pragma unroll
  for (int i = 0; i < 8; ++i)
#pragma unroll
    for (int j = 0; j < 4; ++j) acc[i][j] = (f32x4)0.0f;

  const int NT2 = K >> 7;       // iterations (2 K-tiles each)
  const int nht = (K >> 6) * 4; // total half-tiles

  // prologue: kt0 complete + kt1 B-halves
#pragma unroll
  for (int h = 0; h < 6; ++h) stage(h);
  asm volatile("s_waitcnt vmcnt(4)" ::: "memory");  // kt0 landed (per wave)
  __builtin_amdgcn_s_barrier();                     // all waves

  bf16x8 aF[4][2], bF0[2][2], bF1[2][2];

#pragma unroll 1
  for (int t = 0; t < NT2; ++t) {
#pragma unroll
    for (int g = 0; g < 8; ++g) {
      const int q = g & 3, grp = g >> 2;  // grp == slot being computed
      const bf16* ar = &As[grp][wm][0][0];
      const bf16* br = &Bs[grp][wn >> 1][0][0] + (wn & 1) * 4096;
      if (q == 0) {  // A[mh0] (8) + B[nh0] (4)
#pragma unroll
        for (int mi = 0; mi < 4; ++mi)
#pragma unroll
          for (int ks = 0; ks < 2; ++ks)
            aF[mi][ks] =
                *(const bf16x8*)(ar + (mi * 16 + l15) * 64 + colK[ks]);
#pragma unroll
        for (int ni = 0; ni < 2; ++ni)
#pragma unroll
          for (int ks = 0; ks < 2; ++ks)
            bF0[ni][ks] =
                *(const bf16x8*)(br + (ni * 16 + l15) * 64 + colK[ks]);
      } else if (q == 1) {  // B[nh1] (4)
#pragma unroll
        for (int ni = 0; ni < 2; ++ni)
#pragma unroll
          for (int ks = 0; ks < 2; ++ks)
            bF1[ni][ks] =
                *(const bf16x8*)(br + ((ni + 2) * 16 + l15) * 64 + colK[ks]);
      } else if (q == 2) {  // A[mh1] (8)
#pragma unroll
        for (int mi = 0; mi < 4; ++mi)
#pragma unroll
          for (int ks = 0; ks < 2; ++ks)
            aF[mi][ks] =
                *(const bf16x8*)(ar + ((mi + 4) * 16 + l15) * 64 + colK[ks]);
      }
      // stage one half-tile, lead-2 schedule: ht = 8t + 6 + g
      {
        const int ht = 8 * t + 6 + g;
        if (ht < nht) stage(ht);
      }
      __builtin_amdgcn_sched_barrier(0);
      __builtin_amdgcn_s_barrier();
      __builtin_amdgcn_s_setprio(1);
#pragma unroll
      for (int mi = 0; mi < 4; ++mi)
#pragma unroll
        for (int nj = 0; nj < 2; ++nj)
#pragma unroll
          for (int ks = 0; ks < 2; ++ks)
            acc[mi + (q >= 2 ? 4 : 0)][nj + ((q & 1) ? 2 : 0)] =
                __builtin_amdgcn_mfma_f32_16x16x32_bf16(
                    aF[mi][ks], (q & 1) ? bF1[nj][ks] : bF0[nj][ks],
                    acc[mi + (q >= 2 ? 4 : 0)][nj + ((q & 1) ? 2 : 0)], 0, 0,
                    0);
      __builtin_amdgcn_s_setprio(0);
      if (g == 3) {  // gate: next group reads kt(2t+1)
        if (t == NT2 - 1)
          asm volatile("s_waitcnt vmcnt(0)" ::: "memory");
        else
          asm volatile("s_waitcnt vmcnt(4)" ::: "memory");
      } else if (g == 7) {  // gate: next iter reads kt(2t+2)
        asm volatile("s_waitcnt vmcnt(4)" ::: "memory");
      }
      __builtin_amdgcn_sched_barrier(0);
      __builtin_amdgcn_s_barrier();
    }
  }

  // epilogue: C/D layout col=lane&15, row=(lane>>4)*4+j
#pragma unroll
  for (int mi = 0; mi < 8; ++mi) {
    const int row = m0 + wm * 128 + mi * 16 + (l >> 4) * 4;
#pragma unroll
    for (int ni = 0; ni < 4; ++ni) {
      const int col = n0 + wn * 64 + ni * 16 + l15;
#pragma unroll
      for (int j = 0; j < 4; ++j) {
        float v = acc[mi][ni][j];
        if (EP == 0) {
          ((float*)C)[(size_t)(row + j) * N + col] = v;
        } else {
          const int cls = col >> 10;
          if (cls == 1 || cls == 2) v = fast_sigmoid(v);
          else if (cls == 3) v = fast_tanh(v);
          ((bf16*)C)[(size_t)(row + j) * N + col] = __float2bfloat16(v);
        }
      }
    }
  }
}

// ---------------------------------------------------------------------------
// Fallback fp32-B GEMM (tier-3 out-proj only)
// ---------------------------------------------------------------------------
#define BM 64
#define BN 64
#define BKK 16
__global__ __launch_bounds__(256) void gemm_nt_kernel(
    const bf16* __restrict__ A, const float* __restrict__ B,
    float* __restrict__ C, int M, int N, int K) {
  __shared__ float Asm[BKK][BM + 1];
  __shared__ float Bsm[BKK][BN + 1];
  const int n0 = blockIdx.x * BN;
  const int m0 = blockIdx.y * BM;
  const int tid = threadIdx.x;
  const int tx = tid & 15, ty = tid >> 4;
  const int lk = tid & 15, lr = tid >> 4;
  float acc[4][4] = {};
  for (int k0 = 0; k0 < K; k0 += BKK) {
#pragma unroll
    for (int p = 0; p < 4; ++p) {
      Asm[lk][lr + 16 * p] =
          __bfloat162float(A[(size_t)(m0 + lr + 16 * p) * K + (k0 + lk)]);
      Bsm[lk][lr + 16 * p] = B[(size_t)(n0 + lr + 16 * p) * K + (k0 + lk)];
    }
    __syncthreads();
#pragma unroll
    for (int kk = 0; kk < BKK; ++kk) {
      float a[4], b[4];
#pragma unroll
      for (int i = 0; i < 4; ++i) a[i] = Asm[kk][ty * 4 + i];
#pragma unroll
      for (int j = 0; j < 4; ++j) b[j] = Bsm[kk][tx * 4 + j];
#pragma unroll
      for (int i = 0; i < 4; ++i)
#pragma unroll
        for (int j = 0; j < 4; ++j) acc[i][j] += a[i] * b[j];
    }
    __syncthreads();
  }
#pragma unroll
  for (int i = 0; i < 4; ++i)
#pragma unroll
    for (int j = 0; j < 4; ++j)
      C[(size_t)(m0 + ty * 4 + i) * N + (n0 + tx * 4 + j)] = acc[i][j];
}

// ---------------------------------------------------------------------------
// Chunked scan (u holds already-activated planes v,g,dec,inj in bf16)
// ---------------------------------------------------------------------------
__global__ __launch_bounds__(256) void scan_chunk_kernel(
    const bf16* __restrict__ u, float* __restrict__ cA,
    float* __restrict__ cB, int nchunk, int tchunk) {
  int idx = blockIdx.x * 256 + threadIdx.x;
  int c = idx % DD;
  int chunk = (idx / DD) % nchunk;
  int b = idx / (DD * nchunk);
  const bf16* ub = u + (size_t)b * TT * 4 * DD;
  float Aacc = 1.0f, Bacc = 0.0f;
  int t0 = chunk * tchunk;
  for (int t = t0; t < t0 + tchunk; ++t) {
    const bf16* row = ub + (size_t)t * 4 * DD;
    float dec = __bfloat162float(row[2 * DD + c]);
    float inj = __bfloat162float(row[3 * DD + c]);
    Aacc *= dec;
    Bacc = dec * Bacc + (1.0f - dec) * inj;
  }
  cA[idx] = Aacc;
  cB[idx] = Bacc;
}

__global__ __launch_bounds__(256) void scan_prefix_kernel(
    const float* __restrict__ cA, const float* __restrict__ cB,
    float* __restrict__ S, int nchunk) {
  int idx = blockIdx.x * 256 + threadIdx.x;
  int c = idx % DD;
  int b = idx / DD;
  float s = 0.0f;
  for (int j = 0; j < nchunk; ++j) {
    int e = (b * nchunk + j) * DD + c;
    S[e] = s;
    s = cA[e] * s + cB[e];
  }
}

__global__ __launch_bounds__(256) void scan_out_kernel(
    const bf16* __restrict__ u, const float* __restrict__ S,
    bf16* __restrict__ y, int nchunk, int tchunk) {
  int idx = blockIdx.x * 256 + threadIdx.x;
  int c = idx % DD;
  int chunk = (idx / DD) % nchunk;
  int b = idx / (DD * nchunk);
  const bf16* ub = u + (size_t)b * TT * 4 * DD;
  bf16* yb = y + (size_t)b * TT * DD;
  float state = S[idx];
  int t0 = chunk * tchunk;
  for (int t = t0; t < t0 + tchunk; ++t) {
    const bf16* row = ub + (size_t)t * 4 * DD;
    float v = __bfloat162float(row[c]);
    float g = __bfloat162float(row[DD + c]);
    float dec = __bfloat162float(row[2 * DD + c]);
    float inj = __bfloat162float(row[3 * DD + c]);
    state = dec * state + (1.0f - dec) * inj;
    yb[(size_t)t * DD + c] = __float2bfloat16(g * v + (1.0f - g) * state);
  }
}

// ---------------------------------------------------------------------------
extern "C" void kernel_launch(void* const* d_in, const int* in_sizes, int n_in,
                              void* d_out, int out_size, void* d_ws,
                              size_t ws_size, hipStream_t stream) {
  const float* x = (const float*)d_in[0];
  const float* Wc = (const float*)d_in[1];
  const float* Wp = (const float*)d_in[2];
  const float* Wo = (const float*)d_in[3];
  float* out = (float*)d_out;

  const size_t nb = (size_t)TT * DD;

  auto need = [&](int nbat, int nchunk, bool wob) -> size_t {
    return (size_t)nbat * nb * 2 + (size_t)nbat * 4 * nb * 2 +
           (size_t)4 * DD * DD * 2 + (wob ? (size_t)DD * DD * 2 : 0) +
           (size_t)3 * nbat * nchunk * DD * 4;
  };

  int nbat, nchunk;
  bool haveWob;
  if (ws_size >= need(4, 64, true)) {
    nbat = 4; nchunk = 64; haveWob = true;
  } else if (ws_size >= need(1, 64, true)) {
    nbat = 1; nchunk = 64; haveWob = true;
  } else {
    nbat = 1; nchunk = 16; haveWob = false;
  }
  const int tchunk = TT / nchunk;

  char* p = (char*)d_ws;
  bf16* Wpb = (bf16*)p;  p += (size_t)4 * DD * DD * 2;
  bf16* Wob = nullptr;
  if (haveWob) { Wob = (bf16*)p; p += (size_t)DD * DD * 2; }
  bf16* xm = (bf16*)p;   p += (size_t)nbat * nb * 2;  // also y
  bf16* u = (bf16*)p;    p += (size_t)nbat * 4 * nb * 2;
  float* cA = (float*)p; p += (size_t)nbat * nchunk * DD * 4;
  float* cB = (float*)p; p += (size_t)nbat * nchunk * DD * 4;
  float* S = (float*)p;
  bf16* y = xm;

  w2bf_kernel<<<(4 * DD * DD) / 256, 256, 0, stream>>>(Wp, Wpb, 4 * DD * DD);
  if (haveWob)
    w2bf_kernel<<<(DD * DD) / 256, 256, 0, stream>>>(Wo, Wob, DD * DD);

  for (int b0 = 0; b0 < BB; b0 += nbat) {
    const float* xb = x + (size_t)b0 * nb;
    float* outb = out + (size_t)b0 * nb;
    const int Mtot = nbat * TT;
    const int total = (int)(nbat * nb);

    conv_add_kernel<<<total / 256, 256, 0, stream>>>(xb, Wc, xm, total);

    {  // u = act(xm @ Wp^T): M=Mtot, N=4096, K=1024
      const int MB = Mtot / 256;
      const int nwg = MB * (4 * DD / 256);
      gemm256_kernel<1><<<nwg, 512, 0, stream>>>(xm, Wpb, u, Mtot, 4 * DD, DD,
                                                 MB);
    }
    {
      int nthreads = nbat * nchunk * DD;
      scan_chunk_kernel<<<nthreads / 256, 256, 0, stream>>>(u, cA, cB, nchunk,
                                                            tchunk);
      scan_prefix_kernel<<<(nbat * DD) / 256, 256, 0, stream>>>(cA, cB, S,
                                                                nchunk);
      scan_out_kernel<<<nthreads / 256, 256, 0, stream>>>(u, S, y, nchunk,
                                                          tchunk);
    }
    if (haveWob) {  // out = y @ Wo^T: M=Mtot, N=1024, K=1024
      const int MB = Mtot / 256;
      const int nwg = MB * (DD / 256);
      gemm256_kernel<0><<<nwg, 512, 0, stream>>>(y, Wob, outb, Mtot, DD, DD,
                                                 MB);
    } else {
      dim3 grid(DD / BN, Mtot / BM);
      gemm_nt_kernel<<<grid, 256, 0, stream>>>(y, Wo, outb, Mtot, DD, DD);
    }
  }
}

// Round 5
// 318.020 us; speedup vs baseline: 13.1174x; 1.1710x over previous
//
#include <hip/hip_runtime.h>
#include <hip/hip_bf16.h>
#include <math.h>

typedef __hip_bfloat16 bf16;
typedef __bf16 bf16x8 __attribute__((ext_vector_type(8)));
typedef float f32x4 __attribute__((ext_vector_type(4)));
typedef float f32x4v __attribute__((ext_vector_type(4)));
typedef unsigned short u16x8v __attribute__((ext_vector_type(8)));
typedef unsigned short u16x4v __attribute__((ext_vector_type(4)));

// Problem constants
#define BB 4
#define TT 4096
#define DD 1024

__device__ __forceinline__ float fast_sigmoid(float x) {
  return 1.0f / (1.0f + __expf(-x));
}
__device__ __forceinline__ float fast_tanh(float x) {
  return 2.0f / (1.0f + __expf(-2.0f * x)) - 1.0f;
}
__device__ __forceinline__ float b2f(unsigned short u) {
  union { unsigned int i; float f; } x;
  x.i = ((unsigned int)u) << 16;
  return x.f;
}
__device__ __forceinline__ unsigned short f2b(float f) {
  union { bf16 h; unsigned short u; } x;
  x.h = __float2bfloat16(f);
  return x.u;
}

// ---------------------------------------------------------------------------
// Weight fp32 -> bf16
// ---------------------------------------------------------------------------
__global__ __launch_bounds__(256) void w2bf_kernel(const float* __restrict__ w,
                                                   bf16* __restrict__ o,
                                                   int n) {
  int i = blockIdx.x * 256 + threadIdx.x;
  if (i < n) o[i] = __float2bfloat16(w[i]);
}

// ---------------------------------------------------------------------------
// conv + add -> bf16, 4 channels / thread (float4 loads, 8B store)
// ---------------------------------------------------------------------------
__global__ __launch_bounds__(256) void conv_add_kernel(
    const float* __restrict__ x, const float* __restrict__ Wc,
    bf16* __restrict__ xm, int total4) {
  int i = blockIdx.x * 256 + threadIdx.x;  // over (nbat*TT*DD)/4
  if (i >= total4) return;
  int c4 = (i & (DD / 4 - 1)) * 4;
  int t = (i / (DD / 4)) % TT;
  size_t base = (size_t)i * 4;
  f32x4v x0 = *(const f32x4v*)(x + base);
  f32x4v p1 = (t >= 1) ? *(const f32x4v*)(x + base - DD) : (f32x4v)0.0f;
  f32x4v p2 = (t >= 2) ? *(const f32x4v*)(x + base - 2 * DD) : (f32x4v)0.0f;
  f32x4v p3 = (t >= 3) ? *(const f32x4v*)(x + base - 3 * DD) : (f32x4v)0.0f;
  u16x4v o;
#pragma unroll
  for (int j = 0; j < 4; ++j) {
    f32x4v w = *(const f32x4v*)(Wc + (size_t)(c4 + j) * 4);
    float acc = x0[j] + w[3] * x0[j] + w[2] * p1[j] + w[1] * p2[j] +
                w[0] * p3[j];
    o[j] = f2b(acc);
  }
  *(u16x4v*)(xm + base) = o;
}

// ---------------------------------------------------------------------------
// 256x256 8-phase MFMA GEMM. C[m][n] = sum_k A[m][k]*B[n][k]; A,B bf16,
// K%128==0, M,N%256==0, MB%8==0, grid%8==0. 512 threads = 8 waves (2Mx4N).
// LDS: 2 slots x 2 halves x [128][64] bf16 for A,B = 128 KiB.
// Swizzle (involution on element col, per 128-row half):
//   phys_col = logical_col ^ ((row & 7) << 3)       [16B slot spread, G4]
// staged via pre-swizzled GLOBAL source (LDS dest linear, rule #21).
// XCD map: xcd = bid&7 owns bm-chunk [xcd*MB/8, ...+MB/8), bn-major order
// -> per-XCD A chunk <= 4 MiB stays in its L2.
// EP=0: fp32 C. EP=1: bf16 C with per-1024-col activation.
// ---------------------------------------------------------------------------
template <int EP>
__global__ __launch_bounds__(512) void gemm256_kernel(
    const bf16* __restrict__ A, const bf16* __restrict__ B,
    void* __restrict__ C, int M, int N, int K, int MB) {
  __shared__ __align__(16) bf16 As[2][2][128][64];
  __shared__ __align__(16) bf16 Bs[2][2][128][64];

  const int tid = threadIdx.x;
  const int wv = tid >> 6, l = tid & 63;
  const int wm = wv >> 2, wn = wv & 3;

  // XCD-chunked bijective block mapping
  const int bid = blockIdx.x;
  const int xcd = bid & 7, ii = bid >> 3;
  const int mb8 = MB >> 3;
  const int bm = xcd * mb8 + (ii % mb8);
  const int bn = ii / mb8;
  const int m0 = bm * 256, n0 = bn * 256;

  // staging: segment seg = wv*2+j covers rows seg*8..+7 of a half.
  // lane l -> row seg*8 + (l>>3), phys col el (l&7)*8; source logical col:
  const int lr3 = l >> 3;
  const int gcolE = ((l & 7) ^ (l >> 3)) * 8;
  // frag reads: row = mi*16 + l15 -> row&7 = l15&7.
  const int l15 = l & 15;
  const int rxor = (l15 & 7) << 3;
  const int lhi8 = (l >> 4) * 8;
  const int colK[2] = {lhi8 ^ rxor, (32 + lhi8) ^ rxor};

  const bf16* Arow = A + (size_t)(m0 + wv * 16 + lr3) * K + gcolE;
  const bf16* Brow = B + (size_t)(n0 + wv * 16 + lr3) * K + gcolE;

  // half-tile order within K-tile: 0=B.h0, 1=B.h1, 2=A.h0, 3=A.h1
  auto stage = [&](int ht) {
    const int kt = ht >> 2, which = ht & 3;
    const int slot = kt & 1;
    const int k0 = kt * 64;
    if (which < 2) {
      const int half = which;
#pragma unroll
      for (int j = 0; j < 2; ++j) {
        const bf16* src = Brow + (size_t)(half * 128 + j * 8) * K + k0;
        __builtin_amdgcn_global_load_lds(
            (const __attribute__((address_space(1))) void*)src,
            (__attribute__((address_space(3))) void*)(&Bs[slot][half][0][0] +
                                                      wv * 1024 + j * 512),
            16, 0, 0);
      }
    } else {
      const int half = which - 2;
#pragma unroll
      for (int j = 0; j < 2; ++j) {
        const bf16* src = Arow + (size_t)(half * 128 + j * 8) * K + k0;
        __builtin_amdgcn_global_load_lds(
            (const __attribute__((address_space(1))) void*)src,
            (__attribute__((address_space(3))) void*)(&As[slot][half][0][0] +
                                                      wv * 1024 + j * 512),
            16, 0, 0);
      }
    }
  };

  f32x4 acc[8][4];
#pragma unroll
  for (int i = 0; i < 8; ++i)
#pragma unroll
    for (int j = 0; j < 4; ++j) acc[i][j] = (f32x4)0.0f;

  const int NT2 = K >> 7;        // iterations (2 K-tiles each)
  const int nht = (K >> 6) * 4;  // total half-tiles

  // prologue: kt0 complete + kt1 B-halves
#pragma unroll
  for (int h = 0; h < 6; ++h) stage(h);
  asm volatile("s_waitcnt vmcnt(4)" ::: "memory");  // kt0 landed (per wave)
  __builtin_amdgcn_s_barrier();

  bf16x8 aF[4][2], bF0[2][2], bF1[2][2];

#pragma unroll 1
  for (int t = 0; t < NT2; ++t) {
#pragma unroll
    for (int g = 0; g < 8; ++g) {
      const int q = g & 3, grp = g >> 2;  // grp == slot being computed
      const bf16* ar = &As[grp][wm][0][0];
      const bf16* br = &Bs[grp][wn >> 1][0][0] + (wn & 1) * 4096;
      if (q == 0) {  // A[mh0] (8) + B[nh0] (4)
#pragma unroll
        for (int mi = 0; mi < 4; ++mi)
#pragma unroll
          for (int ks = 0; ks < 2; ++ks)
            aF[mi][ks] =
                *(const bf16x8*)(ar + (mi * 16 + l15) * 64 + colK[ks]);
#pragma unroll
        for (int ni = 0; ni < 2; ++ni)
#pragma unroll
          for (int ks = 0; ks < 2; ++ks)
            bF0[ni][ks] =
                *(const bf16x8*)(br + (ni * 16 + l15) * 64 + colK[ks]);
      } else if (q == 1) {  // B[nh1] (4)
#pragma unroll
        for (int ni = 0; ni < 2; ++ni)
#pragma unroll
          for (int ks = 0; ks < 2; ++ks)
            bF1[ni][ks] =
                *(const bf16x8*)(br + ((ni + 2) * 16 + l15) * 64 + colK[ks]);
      } else if (q == 2) {  // A[mh1] (8)
#pragma unroll
        for (int mi = 0; mi < 4; ++mi)
#pragma unroll
          for (int ks = 0; ks < 2; ++ks)
            aF[mi][ks] =
                *(const bf16x8*)(ar + ((mi + 4) * 16 + l15) * 64 + colK[ks]);
      }
      {  // stage one half-tile, lead-2 schedule
        const int ht = 8 * t + 6 + g;
        if (ht < nht) stage(ht);
      }
      __builtin_amdgcn_sched_barrier(0);
      __builtin_amdgcn_s_barrier();
      __builtin_amdgcn_s_setprio(1);
#pragma unroll
      for (int mi = 0; mi < 4; ++mi)
#pragma unroll
        for (int nj = 0; nj < 2; ++nj)
#pragma unroll
          for (int ks = 0; ks < 2; ++ks)
            acc[mi + (q >= 2 ? 4 : 0)][nj + ((q & 1) ? 2 : 0)] =
                __builtin_amdgcn_mfma_f32_16x16x32_bf16(
                    aF[mi][ks], (q & 1) ? bF1[nj][ks] : bF0[nj][ks],
                    acc[mi + (q >= 2 ? 4 : 0)][nj + ((q & 1) ? 2 : 0)], 0, 0,
                    0);
      __builtin_amdgcn_s_setprio(0);
      if (g == 3) {
        if (t == NT2 - 1)
          asm volatile("s_waitcnt vmcnt(0)" ::: "memory");
        else
          asm volatile("s_waitcnt vmcnt(4)" ::: "memory");
      } else if (g == 7) {
        asm volatile("s_waitcnt vmcnt(4)" ::: "memory");
      }
      __builtin_amdgcn_sched_barrier(0);
      __builtin_amdgcn_s_barrier();
    }
  }

  // epilogue: C/D layout col=lane&15, row=(lane>>4)*4+j
#pragma unroll
  for (int mi = 0; mi < 8; ++mi) {
    const int row = m0 + wm * 128 + mi * 16 + (l >> 4) * 4;
#pragma unroll
    for (int ni = 0; ni < 4; ++ni) {
      const int col = n0 + wn * 64 + ni * 16 + l15;
#pragma unroll
      for (int j = 0; j < 4; ++j) {
        float v = acc[mi][ni][j];
        if (EP == 0) {
          ((float*)C)[(size_t)(row + j) * N + col] = v;
        } else {
          const int cls = col >> 10;
          if (cls == 1 || cls == 2) v = fast_sigmoid(v);
          else if (cls == 3) v = fast_tanh(v);
          ((bf16*)C)[(size_t)(row + j) * N + col] = __float2bfloat16(v);
        }
      }
    }
  }
}

// ---------------------------------------------------------------------------
// Fallback fp32-B GEMM (tier-3 out-proj only)
// ---------------------------------------------------------------------------
#define BM 64
#define BN 64
#define BKK 16
__global__ __launch_bounds__(256) void gemm_nt_kernel(
    const bf16* __restrict__ A, const float* __restrict__ B,
    float* __restrict__ C, int M, int N, int K) {
  __shared__ float Asm[BKK][BM + 1];
  __shared__ float Bsm[BKK][BN + 1];
  const int n0 = blockIdx.x * BN;
  const int m0 = blockIdx.y * BM;
  const int tid = threadIdx.x;
  const int tx = tid & 15, ty = tid >> 4;
  const int lk = tid & 15, lr = tid >> 4;
  float acc[4][4] = {};
  for (int k0 = 0; k0 < K; k0 += BKK) {
#pragma unroll
    for (int p = 0; p < 4; ++p) {
      Asm[lk][lr + 16 * p] =
          __bfloat162float(A[(size_t)(m0 + lr + 16 * p) * K + (k0 + lk)]);
      Bsm[lk][lr + 16 * p] = B[(size_t)(n0 + lr + 16 * p) * K + (k0 + lk)];
    }
    __syncthreads();
#pragma unroll
    for (int kk = 0; kk < BKK; ++kk) {
      float a[4], b[4];
#pragma unroll
      for (int i = 0; i < 4; ++i) a[i] = Asm[kk][ty * 4 + i];
#pragma unroll
      for (int j = 0; j < 4; ++j) b[j] = Bsm[kk][tx * 4 + j];
#pragma unroll
      for (int i = 0; i < 4; ++i)
#pragma unroll
        for (int j = 0; j < 4; ++j) acc[i][j] += a[i] * b[j];
    }
    __syncthreads();
  }
#pragma unroll
  for (int i = 0; i < 4; ++i)
#pragma unroll
    for (int j = 0; j < 4; ++j)
      C[(size_t)(m0 + ty * 4 + i) * N + (n0 + tx * 4 + j)] = acc[i][j];
}

// ---------------------------------------------------------------------------
// Chunked scan, 8 channels/thread (16B bf16 loads)
// ---------------------------------------------------------------------------
__global__ __launch_bounds__(256) void scan_chunk_kernel(
    const bf16* __restrict__ u, float* __restrict__ cA,
    float* __restrict__ cB, int nchunk, int tchunk) {
  int idx = blockIdx.x * 256 + threadIdx.x;  // nbat*nchunk*(DD/8)
  int c8 = (idx & (DD / 8 - 1)) * 8;
  int chunk = (idx / (DD / 8)) % nchunk;
  int b = idx / ((DD / 8) * nchunk);
  const bf16* ub = u + (size_t)b * TT * 4 * DD;
  float Aacc[8], Bacc[8];
#pragma unroll
  for (int j = 0; j < 8; ++j) { Aacc[j] = 1.0f; Bacc[j] = 0.0f; }
  int t0 = chunk * tchunk;
  for (int t = t0; t < t0 + tchunk; ++t) {
    const bf16* row = ub + (size_t)t * 4 * DD;
    u16x8v dv = *(const u16x8v*)(row + 2 * DD + c8);
    u16x8v iv = *(const u16x8v*)(row + 3 * DD + c8);
#pragma unroll
    for (int j = 0; j < 8; ++j) {
      float dec = b2f(dv[j]), inj = b2f(iv[j]);
      Aacc[j] *= dec;
      Bacc[j] = dec * Bacc[j] + (1.0f - dec) * inj;
    }
  }
  int base = (b * nchunk + chunk) * DD + c8;
#pragma unroll
  for (int j = 0; j < 8; ++j) { cA[base + j] = Aacc[j]; cB[base + j] = Bacc[j]; }
}

__global__ __launch_bounds__(256) void scan_prefix_kernel(
    const float* __restrict__ cA, const float* __restrict__ cB,
    float* __restrict__ S, int nchunk) {
  int idx = blockIdx.x * 256 + threadIdx.x;  // nbat*DD
  int c = idx % DD;
  int b = idx / DD;
  float s = 0.0f;
  for (int j = 0; j < nchunk; ++j) {
    int e = (b * nchunk + j) * DD + c;
    S[e] = s;
    s = cA[e] * s + cB[e];
  }
}

__global__ __launch_bounds__(256) void scan_out_kernel(
    const bf16* __restrict__ u, const float* __restrict__ S,
    bf16* __restrict__ y, int nchunk, int tchunk) {
  int idx = blockIdx.x * 256 + threadIdx.x;  // nbat*nchunk*(DD/8)
  int c8 = (idx & (DD / 8 - 1)) * 8;
  int chunk = (idx / (DD / 8)) % nchunk;
  int b = idx / ((DD / 8) * nchunk);
  const bf16* ub = u + (size_t)b * TT * 4 * DD;
  bf16* yb = y + (size_t)b * TT * DD;
  float st[8];
  int sbase = (b * nchunk + chunk) * DD + c8;
#pragma unroll
  for (int j = 0; j < 8; ++j) st[j] = S[sbase + j];
  int t0 = chunk * tchunk;
  for (int t = t0; t < t0 + tchunk; ++t) {
    const bf16* row = ub + (size_t)t * 4 * DD;
    u16x8v vv = *(const u16x8v*)(row + c8);
    u16x8v gv = *(const u16x8v*)(row + DD + c8);
    u16x8v dv = *(const u16x8v*)(row + 2 * DD + c8);
    u16x8v iv = *(const u16x8v*)(row + 3 * DD + c8);
    u16x8v ov;
#pragma unroll
    for (int j = 0; j < 8; ++j) {
      float dec = b2f(dv[j]), inj = b2f(iv[j]);
      float g = b2f(gv[j]), v = b2f(vv[j]);
      st[j] = dec * st[j] + (1.0f - dec) * inj;
      ov[j] = f2b(g * v + (1.0f - g) * st[j]);
    }
    *(u16x8v*)(yb + (size_t)t * DD + c8) = ov;
  }
}

// ---------------------------------------------------------------------------
extern "C" void kernel_launch(void* const* d_in, const int* in_sizes, int n_in,
                              void* d_out, int out_size, void* d_ws,
                              size_t ws_size, hipStream_t stream) {
  const float* x = (const float*)d_in[0];
  const float* Wc = (const float*)d_in[1];
  const float* Wp = (const float*)d_in[2];
  const float* Wo = (const float*)d_in[3];
  float* out = (float*)d_out;

  const size_t nb = (size_t)TT * DD;

  auto need = [&](int nbat, int nchunk, bool wob) -> size_t {
    return (size_t)nbat * nb * 2 + (size_t)nbat * 4 * nb * 2 +
           (size_t)4 * DD * DD * 2 + (wob ? (size_t)DD * DD * 2 : 0) +
           (size_t)3 * nbat * nchunk * DD * 4;
  };

  int nbat, nchunk;
  bool haveWob;
  if (ws_size >= need(4, 64, true)) {
    nbat = 4; nchunk = 64; haveWob = true;
  } else if (ws_size >= need(1, 64, true)) {
    nbat = 1; nchunk = 64; haveWob = true;
  } else {
    nbat = 1; nchunk = 16; haveWob = false;
  }
  const int tchunk = TT / nchunk;

  char* p = (char*)d_ws;
  bf16* Wpb = (bf16*)p;  p += (size_t)4 * DD * DD * 2;
  bf16* Wob = nullptr;
  if (haveWob) { Wob = (bf16*)p; p += (size_t)DD * DD * 2; }
  bf16* xm = (bf16*)p;   p += (size_t)nbat * nb * 2;  // also y
  bf16* u = (bf16*)p;    p += (size_t)nbat * 4 * nb * 2;
  float* cA = (float*)p; p += (size_t)nbat * nchunk * DD * 4;
  float* cB = (float*)p; p += (size_t)nbat * nchunk * DD * 4;
  float* S = (float*)p;
  bf16* y = xm;

  w2bf_kernel<<<(4 * DD * DD) / 256, 256, 0, stream>>>(Wp, Wpb, 4 * DD * DD);
  if (haveWob)
    w2bf_kernel<<<(DD * DD) / 256, 256, 0, stream>>>(Wo, Wob, DD * DD);

  for (int b0 = 0; b0 < BB; b0 += nbat) {
    const float* xb = x + (size_t)b0 * nb;
    float* outb = out + (size_t)b0 * nb;
    const int Mtot = nbat * TT;
    const int total4 = (int)(nbat * nb / 4);

    conv_add_kernel<<<total4 / 256, 256, 0, stream>>>(xb, Wc, xm, total4);

    {  // u = act(xm @ Wp^T): M=Mtot, N=4096, K=1024
      const int MB = Mtot / 256;
      const int nwg = MB * (4 * DD / 256);
      gemm256_kernel<1><<<nwg, 512, 0, stream>>>(xm, Wpb, u, Mtot, 4 * DD, DD,
                                                 MB);
    }
    {
      int nthreads = nbat * nchunk * (DD / 8);
      scan_chunk_kernel<<<nthreads / 256, 256, 0, stream>>>(u, cA, cB, nchunk,
                                                            tchunk);
      scan_prefix_kernel<<<(nbat * DD) / 256, 256, 0, stream>>>(cA, cB, S,
                                                                nchunk);
      scan_out_kernel<<<nthreads / 256, 256, 0, stream>>>(u, S, y, nchunk,
                                                          tchunk);
    }
    if (haveWob) {  // out = y @ Wo^T: M=Mtot, N=1024, K=1024
      const int MB = Mtot / 256;
      const int nwg = MB * (DD / 256);
      gemm256_kernel<0><<<nwg, 512, 0, stream>>>(y, Wob, outb, Mtot, DD, DD,
                                                 MB);
    } else {
      dim3 grid(DD / BN, Mtot / BM);
      gemm_nt_kernel<<<grid, 256, 0, stream>>>(y, Wo, outb, Mtot, DD, DD);
    }
  }
}

// Round 6
// 315.669 us; speedup vs baseline: 13.2151x; 1.0074x over previous
//
#include <hip/hip_runtime.h>
#include <hip/hip_bf16.h>
#include <math.h>

typedef __hip_bfloat16 bf16;
typedef __bf16 bf16x8 __attribute__((ext_vector_type(8)));
typedef float f32x4 __attribute__((ext_vector_type(4)));
typedef float f32x4v __attribute__((ext_vector_type(4)));
typedef unsigned short u16x8v __attribute__((ext_vector_type(8)));
typedef unsigned short u16x4v __attribute__((ext_vector_type(4)));

// Problem constants
#define BB 4
#define TT 4096
#define DD 1024

__device__ __forceinline__ float fast_sigmoid(float x) {
  return 1.0f / (1.0f + __expf(-x));
}
__device__ __forceinline__ float fast_tanh(float x) {
  return 2.0f / (1.0f + __expf(-2.0f * x)) - 1.0f;
}
__device__ __forceinline__ float b2f(unsigned short u) {
  union { unsigned int i; float f; } x;
  x.i = ((unsigned int)u) << 16;
  return x.f;
}
__device__ __forceinline__ unsigned short f2b(float f) {
  union { bf16 h; unsigned short u; } x;
  x.h = __float2bfloat16(f);
  return x.u;
}

// ---------------------------------------------------------------------------
// Weight fp32 -> bf16
// ---------------------------------------------------------------------------
__global__ __launch_bounds__(256) void w2bf_kernel(const float* __restrict__ w,
                                                   bf16* __restrict__ o,
                                                   int n) {
  int i = blockIdx.x * 256 + threadIdx.x;
  if (i < n) o[i] = __float2bfloat16(w[i]);
}

// ---------------------------------------------------------------------------
// conv + add -> bf16, 4 channels / thread
// ---------------------------------------------------------------------------
__global__ __launch_bounds__(256) void conv_add_kernel(
    const float* __restrict__ x, const float* __restrict__ Wc,
    bf16* __restrict__ xm, int total4) {
  int i = blockIdx.x * 256 + threadIdx.x;
  if (i >= total4) return;
  int c4 = (i & (DD / 4 - 1)) * 4;
  int t = (i / (DD / 4)) % TT;
  size_t base = (size_t)i * 4;
  f32x4v x0 = *(const f32x4v*)(x + base);
  f32x4v p1 = (t >= 1) ? *(const f32x4v*)(x + base - DD) : (f32x4v)0.0f;
  f32x4v p2 = (t >= 2) ? *(const f32x4v*)(x + base - 2 * DD) : (f32x4v)0.0f;
  f32x4v p3 = (t >= 3) ? *(const f32x4v*)(x + base - 3 * DD) : (f32x4v)0.0f;
  u16x4v o;
#pragma unroll
  for (int j = 0; j < 4; ++j) {
    f32x4v w = *(const f32x4v*)(Wc + (size_t)(c4 + j) * 4);
    float acc = x0[j] + w[3] * x0[j] + w[2] * p1[j] + w[1] * p2[j] +
                w[0] * p3[j];
    o[j] = f2b(acc);
  }
  *(u16x4v*)(xm + base) = o;
}

// ---------------------------------------------------------------------------
// 256x256 8-phase MFMA GEMM. C[m][n] = sum_k A[m][k]*B[n][k]; A,B bf16,
// K%128==0, M,N%256==0, MB%8==0. 512 threads = 8 waves (2Mx4N).
// LDS: 2 slots x 2 halves x [128][64] bf16 for A,B = 128 KiB.
// Swizzle involution on 8-elem slots: phys = log ^ (row & 7).
// Lead-3 half-tile prefetch, vmcnt(6) gates at phases 4/8 (template-exact).
// All frag-read LDS addresses = 4 lane-base regs + compile-time offsets.
// EP=0: fp32 C. EP=1: bf16 C with per-1024-col activation.
// ---------------------------------------------------------------------------
template <int EP>
__global__ __launch_bounds__(512, 2) void gemm256_kernel(
    const bf16* __restrict__ A, const bf16* __restrict__ B,
    void* __restrict__ C, int M, int N, int K, int MB) {
  __shared__ __align__(16) bf16 As[2][2][128][64];
  __shared__ __align__(16) bf16 Bs[2][2][128][64];

  const int tid = threadIdx.x;
  const int wv = tid >> 6, l = tid & 63;
  const int wm = wv >> 2, wn = wv & 3;

  // XCD-chunked bijective block mapping
  const int bid = blockIdx.x;
  const int xcd = bid & 7, ii = bid >> 3;
  const int mb8 = MB >> 3;
  const int bm = xcd * mb8 + (ii % mb8);
  const int bn = ii / mb8;
  const int m0 = bm * 256, n0 = bn * 256;

  // staging: lane l -> row seg*8 + (l>>3), phys slot (l&7)^(l>>3)
  const int lr3 = l >> 3;
  const int gcolE = ((l & 7) ^ (l >> 3)) * 8;
  // frag reads: row = mi*16 + l15 -> row&7 = l15&7
  const int l15 = l & 15;
  const int rxor = (l15 & 7) << 3;
  const int lhi8 = (l >> 4) * 8;
  const int colK0 = lhi8 ^ rxor;
  const int colK1 = (32 + lhi8) ^ rxor;

  // hoisted LDS byte bases (4 regs); all reads = base + const offset
  const char* AsB = (const char*)&As[0][0][0][0];
  const char* BsB = (const char*)&Bs[0][0][0][0];
  const int aB0 = wm * 16384 + l15 * 128 + colK0 * 2;
  const int aB1 = wm * 16384 + l15 * 128 + colK1 * 2;
  const int bB0 = (wn >> 1) * 16384 + (wn & 1) * 8192 + l15 * 128 + colK0 * 2;
  const int bB1 = (wn >> 1) * 16384 + (wn & 1) * 8192 + l15 * 128 + colK1 * 2;

  const bf16* Arow = A + (size_t)(m0 + wv * 16 + lr3) * K + gcolE;
  const bf16* Brow = B + (size_t)(n0 + wv * 16 + lr3) * K + gcolE;
  const bf16* ArowH = Arow + (size_t)128 * K;
  const bf16* BrowH = Brow + (size_t)128 * K;

  bf16* AsW = &As[0][0][0][0];
  bf16* BsW = &Bs[0][0][0][0];

  // stage one half-tile: which 0=B.h0 1=B.h1 2=A.h0 3=A.h1 (which literal!)
  auto stage1 = [&](int which, int k0) {
    const int slot = (k0 >> 6) & 1;
    const bf16* src0 =
        (which == 0 ? Brow : which == 1 ? BrowH : which == 2 ? Arow : ArowH) +
        k0;
    bf16* dst0 = (which < 2 ? BsW : AsW) + slot * 16384 + (which & 1) * 8192 +
                 wv * 1024;
#pragma unroll
    for (int j = 0; j < 2; ++j) {
      __builtin_amdgcn_global_load_lds(
          (const __attribute__((address_space(1))) void*)(src0 +
                                                          (size_t)(j * 8) * K),
          (__attribute__((address_space(3))) void*)(dst0 + j * 512), 16, 0, 0);
    }
  };

  f32x4 acc[8][4];
#pragma unroll
  for (int i = 0; i < 8; ++i)
#pragma unroll
    for (int j = 0; j < 4; ++j) acc[i][j] = (f32x4)0.0f;

  const int NT2 = K >> 7;  // iterations (2 K-tiles each)

  // prologue: ht 0..6 = kt0 full + kt1 {B.h0,B.h1,A.h0}
  stage1(0, 0); stage1(1, 0); stage1(2, 0); stage1(3, 0);
  stage1(0, 64); stage1(1, 64); stage1(2, 64);
  asm volatile("s_waitcnt vmcnt(6)" ::: "memory");  // kt0 landed
  __builtin_amdgcn_s_barrier();

  bf16x8 aF[4][2], bF0[2][2], bF1[2][2];

  int kb = 0;  // 128*t
#pragma unroll 1
  for (int t = 0; t < NT2; ++t, kb += 128) {
#pragma unroll
    for (int g = 0; g < 8; ++g) {
      const int q = g & 3, grp = g >> 2;  // grp == slot being computed
      const int gof = grp * 32768;
      if (q == 0) {  // A[mh0] (8 reads) + B[nh0] (4 reads)
#pragma unroll
        for (int mi = 0; mi < 4; ++mi) {
          aF[mi][0] = *(const bf16x8*)(AsB + aB0 + gof + mi * 2048);
          aF[mi][1] = *(const bf16x8*)(AsB + aB1 + gof + mi * 2048);
        }
#pragma unroll
        for (int ni = 0; ni < 2; ++ni) {
          bF0[ni][0] = *(const bf16x8*)(BsB + bB0 + gof + ni * 2048);
          bF0[ni][1] = *(const bf16x8*)(BsB + bB1 + gof + ni * 2048);
        }
      } else if (q == 1) {  // B[nh1] (4 reads)
#pragma unroll
        for (int ni = 0; ni < 2; ++ni) {
          bF1[ni][0] = *(const bf16x8*)(BsB + bB0 + gof + (ni + 2) * 2048);
          bF1[ni][1] = *(const bf16x8*)(BsB + bB1 + gof + (ni + 2) * 2048);
        }
      } else if (q == 2) {  // A[mh1] (8 reads)
#pragma unroll
        for (int mi = 0; mi < 4; ++mi) {
          aF[mi][0] = *(const bf16x8*)(AsB + aB0 + gof + (mi + 4) * 2048);
          aF[mi][1] = *(const bf16x8*)(AsB + aB1 + gof + (mi + 4) * 2048);
        }
      }
      // stage one half-tile, lead-3: ht = 8t+7+g
      if (t < NT2 - 1 || g == 0)
        stage1((7 + g) & 3, kb + 64 * ((7 + g) >> 2));
      __builtin_amdgcn_sched_barrier(0);
      __builtin_amdgcn_s_barrier();
      __builtin_amdgcn_s_setprio(1);
#pragma unroll
      for (int ks = 0; ks < 2; ++ks)
#pragma unroll
        for (int mi = 0; mi < 4; ++mi)
#pragma unroll
          for (int nj = 0; nj < 2; ++nj)
            acc[mi + (q >= 2 ? 4 : 0)][nj + ((q & 1) ? 2 : 0)] =
                __builtin_amdgcn_mfma_f32_16x16x32_bf16(
                    aF[mi][ks], (q & 1) ? bF1[nj][ks] : bF0[nj][ks],
                    acc[mi + (q >= 2 ? 4 : 0)][nj + ((q & 1) ? 2 : 0)], 0, 0,
                    0);
      __builtin_amdgcn_s_setprio(0);
      if (q == 3) {
        if (g == 3 && t == NT2 - 1)
          asm volatile("s_waitcnt vmcnt(0)" ::: "memory");
        else
          asm volatile("s_waitcnt vmcnt(6)" ::: "memory");
        __builtin_amdgcn_sched_barrier(0);
      }
      __builtin_amdgcn_s_barrier();
    }
  }

  // epilogue: C/D layout col=lane&15, row=(lane>>4)*4+j
#pragma unroll
  for (int mi = 0; mi < 8; ++mi) {
    const int row = m0 + wm * 128 + mi * 16 + (l >> 4) * 4;
#pragma unroll
    for (int ni = 0; ni < 4; ++ni) {
      const int col = n0 + wn * 64 + ni * 16 + l15;
#pragma unroll
      for (int j = 0; j < 4; ++j) {
        float v = acc[mi][ni][j];
        if (EP == 0) {
          ((float*)C)[(size_t)(row + j) * N + col] = v;
        } else {
          const int cls = col >> 10;
          if (cls == 1 || cls == 2) v = fast_sigmoid(v);
          else if (cls == 3) v = fast_tanh(v);
          ((bf16*)C)[(size_t)(row + j) * N + col] = __float2bfloat16(v);
        }
      }
    }
  }
}

// ---------------------------------------------------------------------------
// Fallback fp32-B GEMM (tier-3 out-proj only)
// ---------------------------------------------------------------------------
#define BM 64
#define BN 64
#define BKK 16
__global__ __launch_bounds__(256) void gemm_nt_kernel(
    const bf16* __restrict__ A, const float* __restrict__ B,
    float* __restrict__ C, int M, int N, int K) {
  __shared__ float Asm[BKK][BM + 1];
  __shared__ float Bsm[BKK][BN + 1];
  const int n0 = blockIdx.x * BN;
  const int m0 = blockIdx.y * BM;
  const int tid = threadIdx.x;
  const int tx = tid & 15, ty = tid >> 4;
  const int lk = tid & 15, lr = tid >> 4;
  float acc[4][4] = {};
  for (int k0 = 0; k0 < K; k0 += BKK) {
#pragma unroll
    for (int p = 0; p < 4; ++p) {
      Asm[lk][lr + 16 * p] =
          __bfloat162float(A[(size_t)(m0 + lr + 16 * p) * K + (k0 + lk)]);
      Bsm[lk][lr + 16 * p] = B[(size_t)(n0 + lr + 16 * p) * K + (k0 + lk)];
    }
    __syncthreads();
#pragma unroll
    for (int kk = 0; kk < BKK; ++kk) {
      float a[4], b[4];
#pragma unroll
      for (int i = 0; i < 4; ++i) a[i] = Asm[kk][ty * 4 + i];
#pragma unroll
      for (int j = 0; j < 4; ++j) b[j] = Bsm[kk][tx * 4 + j];
#pragma unroll
      for (int i = 0; i < 4; ++i)
#pragma unroll
        for (int j = 0; j < 4; ++j) acc[i][j] += a[i] * b[j];
    }
    __syncthreads();
  }
#pragma unroll
  for (int i = 0; i < 4; ++i)
#pragma unroll
    for (int j = 0; j < 4; ++j)
      C[(size_t)(m0 + ty * 4 + i) * N + (n0 + tx * 4 + j)] = acc[i][j];
}

// ---------------------------------------------------------------------------
// Chunked scan, 8 channels/thread (16B bf16 loads)
// ---------------------------------------------------------------------------
__global__ __launch_bounds__(256) void scan_chunk_kernel(
    const bf16* __restrict__ u, float* __restrict__ cA,
    float* __restrict__ cB, int nchunk, int tchunk) {
  int idx = blockIdx.x * 256 + threadIdx.x;
  int c8 = (idx & (DD / 8 - 1)) * 8;
  int chunk = (idx / (DD / 8)) % nchunk;
  int b = idx / ((DD / 8) * nchunk);
  const bf16* ub = u + (size_t)b * TT * 4 * DD;
  float Aacc[8], Bacc[8];
#pragma unroll
  for (int j = 0; j < 8; ++j) { Aacc[j] = 1.0f; Bacc[j] = 0.0f; }
  int t0 = chunk * tchunk;
  for (int t = t0; t < t0 + tchunk; ++t) {
    const bf16* row = ub + (size_t)t * 4 * DD;
    u16x8v dv = *(const u16x8v*)(row + 2 * DD + c8);
    u16x8v iv = *(const u16x8v*)(row + 3 * DD + c8);
#pragma unroll
    for (int j = 0; j < 8; ++j) {
      float dec = b2f(dv[j]), inj = b2f(iv[j]);
      Aacc[j] *= dec;
      Bacc[j] = dec * Bacc[j] + (1.0f - dec) * inj;
    }
  }
  int base = (b * nchunk + chunk) * DD + c8;
#pragma unroll
  for (int j = 0; j < 8; ++j) { cA[base + j] = Aacc[j]; cB[base + j] = Bacc[j]; }
}

__global__ __launch_bounds__(256) void scan_prefix_kernel(
    const float* __restrict__ cA, const float* __restrict__ cB,
    float* __restrict__ S, int nchunk) {
  int idx = blockIdx.x * 256 + threadIdx.x;
  int c = idx % DD;
  int b = idx / DD;
  float s = 0.0f;
  for (int j = 0; j < nchunk; ++j) {
    int e = (b * nchunk + j) * DD + c;
    S[e] = s;
    s = cA[e] * s + cB[e];
  }
}

__global__ __launch_bounds__(256) void scan_out_kernel(
    const bf16* __restrict__ u, const float* __restrict__ S,
    bf16* __restrict__ y, int nchunk, int tchunk) {
  int idx = blockIdx.x * 256 + threadIdx.x;
  int c8 = (idx & (DD / 8 - 1)) * 8;
  int chunk = (idx / (DD / 8)) % nchunk;
  int b = idx / ((DD / 8) * nchunk);
  const bf16* ub = u + (size_t)b * TT * 4 * DD;
  bf16* yb = y + (size_t)b * TT * DD;
  float st[8];
  int sbase = (b * nchunk + chunk) * DD + c8;
#pragma unroll
  for (int j = 0; j < 8; ++j) st[j] = S[sbase + j];
  int t0 = chunk * tchunk;
  for (int t = t0; t < t0 + tchunk; ++t) {
    const bf16* row = ub + (size_t)t * 4 * DD;
    u16x8v vv = *(const u16x8v*)(row + c8);
    u16x8v gv = *(const u16x8v*)(row + DD + c8);
    u16x8v dv = *(const u16x8v*)(row + 2 * DD + c8);
    u16x8v iv = *(const u16x8v*)(row + 3 * DD + c8);
    u16x8v ov;
#pragma unroll
    for (int j = 0; j < 8; ++j) {
      float dec = b2f(dv[j]), inj = b2f(iv[j]);
      float g = b2f(gv[j]), v = b2f(vv[j]);
      st[j] = dec * st[j] + (1.0f - dec) * inj;
      ov[j] = f2b(g * v + (1.0f - g) * st[j]);
    }
    *(u16x8v*)(yb + (size_t)t * DD + c8) = ov;
  }
}

// ---------------------------------------------------------------------------
extern "C" void kernel_launch(void* const* d_in, const int* in_sizes, int n_in,
                              void* d_out, int out_size, void* d_ws,
                              size_t ws_size, hipStream_t stream) {
  const float* x = (const float*)d_in[0];
  const float* Wc = (const float*)d_in[1];
  const float* Wp = (const float*)d_in[2];
  const float* Wo = (const float*)d_in[3];
  float* out = (float*)d_out;

  const size_t nb = (size_t)TT * DD;

  auto need = [&](int nbat, int nchunk, bool wob) -> size_t {
    return (size_t)nbat * nb * 2 + (size_t)nbat * 4 * nb * 2 +
           (size_t)4 * DD * DD * 2 + (wob ? (size_t)DD * DD * 2 : 0) +
           (size_t)3 * nbat * nchunk * DD * 4;
  };

  int nbat, nchunk;
  bool haveWob;
  if (ws_size >= need(4, 64, true)) {
    nbat = 4; nchunk = 64; haveWob = true;
  } else if (ws_size >= need(1, 64, true)) {
    nbat = 1; nchunk = 64; haveWob = true;
  } else {
    nbat = 1; nchunk = 16; haveWob = false;
  }
  const int tchunk = TT / nchunk;

  char* p = (char*)d_ws;
  bf16* Wpb = (bf16*)p;  p += (size_t)4 * DD * DD * 2;
  bf16* Wob = nullptr;
  if (haveWob) { Wob = (bf16*)p; p += (size_t)DD * DD * 2; }
  bf16* xm = (bf16*)p;   p += (size_t)nbat * nb * 2;  // also y
  bf16* u = (bf16*)p;    p += (size_t)nbat * 4 * nb * 2;
  float* cA = (float*)p; p += (size_t)nbat * nchunk * DD * 4;
  float* cB = (float*)p; p += (size_t)nbat * nchunk * DD * 4;
  float* S = (float*)p;
  bf16* y = xm;

  w2bf_kernel<<<(4 * DD * DD) / 256, 256, 0, stream>>>(Wp, Wpb, 4 * DD * DD);
  if (haveWob)
    w2bf_kernel<<<(DD * DD) / 256, 256, 0, stream>>>(Wo, Wob, DD * DD);

  for (int b0 = 0; b0 < BB; b0 += nbat) {
    const float* xb = x + (size_t)b0 * nb;
    float* outb = out + (size_t)b0 * nb;
    const int Mtot = nbat * TT;
    const int total4 = (int)(nbat * nb / 4);

    conv_add_kernel<<<total4 / 256, 256, 0, stream>>>(xb, Wc, xm, total4);

    {  // u = act(xm @ Wp^T): M=Mtot, N=4096, K=1024
      const int MB = Mtot / 256;
      const int nwg = MB * (4 * DD / 256);
      gemm256_kernel<1><<<nwg, 512, 0, stream>>>(xm, Wpb, u, Mtot, 4 * DD, DD,
                                                 MB);
    }
    {
      int nthreads = nbat * nchunk * (DD / 8);
      scan_chunk_kernel<<<nthreads / 256, 256, 0, stream>>>(u, cA, cB, nchunk,
                                                            tchunk);
      scan_prefix_kernel<<<(nbat * DD) / 256, 256, 0, stream>>>(cA, cB, S,
                                                                nchunk);
      scan_out_kernel<<<nthreads / 256, 256, 0, stream>>>(u, S, y, nchunk,
                                                          tchunk);
    }
    if (haveWob) {  // out = y @ Wo^T: M=Mtot, N=1024, K=1024
      const int MB = Mtot / 256;
      const int nwg = MB * (DD / 256);
      gemm256_kernel<0><<<nwg, 512, 0, stream>>>(y, Wob, outb, Mtot, DD, DD,
                                                 MB);
    } else {
      dim3 grid(DD / BN, Mtot / BM);
      gemm_nt_kernel<<<grid, 256, 0, stream>>>(y, Wo, outb, Mtot, DD, DD);
    }
  }
}